// Round 8
// baseline (906.692 us; speedup 1.0000x reference)
//
#include <hip/hip_runtime.h>

typedef __attribute__((ext_vector_type(4))) float f32x4;
typedef __attribute__((ext_vector_type(8))) _Float16 f16x8;

#define NSRC 8192
#define MANC 4096
#define QDIM 4096
#define VDIM 512
#define DM   1024
#define FFD  2048

__device__ __forceinline__ ushort f2h(float f){ _Float16 h=(_Float16)f; return __builtin_bit_cast(ushort,h); }
__device__ __forceinline__ float h2f(ushort u){ _Float16 h=__builtin_bit_cast(_Float16,u); return (float)h; }
__device__ __forceinline__ uint pk2(float a,float b){ return (uint)f2h(a) | ((uint)f2h(b)<<16); }

__device__ __forceinline__ void gload16(const ushort* g, ushort* l){
  __builtin_amdgcn_global_load_lds(
    (const __attribute__((address_space(1))) unsigned int*)g,
    (__attribute__((address_space(3))) unsigned int*)l, 16, 0, 0);
}

// ---------- f32 -> f16 convert (src only) ----------
__global__ __launch_bounds__(256) void k_conv(const float* __restrict__ in, ushort* __restrict__ out, long n){
  long i = ((long)blockIdx.x*256 + threadIdx.x)*8;
  if (i >= n) return;
  float4 a = *(const float4*)(in+i);
  float4 b = *(const float4*)(in+i+4);
  uint4 o; o.x=pk2(a.x,a.y); o.y=pk2(a.z,a.w); o.z=pk2(b.x,b.y); o.w=pk2(b.z,b.w);
  *(uint4*)(out+i) = o;
}

// ---------- merged weight transposes: W[K][N] f32 -> WT[N][K] f16 ----------
__device__ __forceinline__ void tr32(const float* __restrict__ W, ushort* __restrict__ WT,
                                     int K, int N, int bx, int by, int tid){
  __shared__ float tile[32][33];
  int n0 = bx*32, k0 = by*32;
  int tx = tid & 31, ty = tid >> 5;
  #pragma unroll
  for (int i=0;i<4;++i) tile[ty+i*8][tx] = W[(long)(k0+ty+i*8)*N + n0+tx];
  __syncthreads();
  #pragma unroll
  for (int i=0;i<4;++i){ int nn=ty+i*8; WT[(long)(n0+nn)*K + k0+tx] = f2h(tile[tx][nn]); }
}
__global__ __launch_bounds__(256) void k_prep(const float* __restrict__ Wq, const float* __restrict__ Wv,
    const float* __restrict__ W1, const float* __restrict__ W2, const float* __restrict__ Wd,
    ushort* __restrict__ WqT, ushort* __restrict__ WvT, ushort* __restrict__ W1T,
    ushort* __restrict__ W2T, ushort* __restrict__ WdT){
  int b = blockIdx.x, t = threadIdx.x;
  if (b < 4096)                 tr32(Wq, WqT, QDIM, DM,  b % 32,        b / 32,        t);
  else if (b < 4608)            tr32(Wv, WvT, VDIM, DM,  (b-4096)%32,   (b-4096)/32,   t);
  else if (b < 6656)            tr32(W1, W1T, DM,  FFD,  (b-4608)%64,   (b-4608)/64,   t);
  else if (b < 8704)            tr32(W2, W2T, FFD, DM,   (b-6656)%32,   (b-6656)/32,   t);
  else                          tr32(Wd, WdT, DM,  VDIM, (b-8704)%16,   (b-8704)/16,   t);
}

// ============ 16-wave TLP GEMM: 1024 thr, 256xBN tile, double-buffered ============
// C[M,N] = A[M,K](f16) * Bt[N,K]^T(f16). One block = 16 waves = 4 waves/SIMD (the
// TLP that all prior 2-wave/SIMD schedules lacked). BIG: BN=256, per-wave 64x64
// (acc[4][4]), LDS 2x64KB = 128KB. SMALL: BN=128, per-wave 64x32 (acc[4][2]),
// LDS 2x48KB = 96KB. Per K-tile: stage t+1 into buf^1 (issued FIRST, a full tile
// of latency lead), read frags from buf, MFMA, one __syncthreads (drains vm+lgkm;
// also makes buf^1 ready and buf reusable next tile).
// EPI: 0 f16+bias | 2 f16 *alpha*extra(f32) | 3 f32 *alpha | 4 f16 tanh(+bias) | 5 f32 +bias+extra(f16)
template<int EPI, int BIG>
__global__ __launch_bounds__(1024) void k_gemmT(const ushort* __restrict__ A, const ushort* __restrict__ Bt,
    int M, int N, int K, const float* __restrict__ bias, const void* __restrict__ extra,
    float alpha, float* __restrict__ Cf, ushort* __restrict__ Ch, int gxm1, int lg2gx)
{
  extern __shared__ ushort lds[];
  constexpr int BN   = BIG ? 256 : 128;
  constexpr int NI   = BIG ? 4 : 2;          // acc cols per wave
  constexpr int WN   = NI * 16;              // per-wave N width
  constexpr int BSH  = BIG ? 16384 : 8192;   // shorts per B buffer
  constexpr int HALF = 16384 + BSH;          // shorts per (A,B) buffer
  constexpr int BJ   = BIG ? 2 : 1;          // B stage loads per thread
  const int tid = threadIdx.x, lane = tid & 63, w = tid >> 6;
  const int wm = (w >> 2) * 64, wn = (w & 3) * WN;
  int id = blockIdx.x;
  int nid = (id & 7) * ((int)gridDim.x >> 3) + (id >> 3);
  const int m0 = (nid >> lg2gx) * 256, n0 = (nid & gxm1) * BN;
  const int lr = lane & 15, kg = lane >> 4;
  f32x4 acc[4][NI] = {};
  const int nkt = K >> 6;
  const ushort* Ap = A + (long)m0 * K;
  const ushort* Bp = Bt + (long)n0 * K;
  // staging map: 16B chunk c -> row c>>3, col-chunk (c&7)^(row&7) (XOR both sides)
  int ra[2], ca[2];
  #pragma unroll
  for (int j = 0; j < 2; ++j){ int c = j*1024 + tid; ra[j] = c >> 3; ca[j] = (c & 7) ^ (ra[j] & 7); }
  auto stage = [&](int t, int buf){
    long ko = (long)t * 64;
    ushort* As = lds + buf*HALF;
    ushort* Bs = As + 16384;
    #pragma unroll
    for (int j = 0; j < 2; ++j)  gload16(Ap + (long)ra[j]*K + ko + ca[j]*8, As + (j*1024 + tid)*8);
    #pragma unroll
    for (int j = 0; j < BJ; ++j) gload16(Bp + (long)ra[j]*K + ko + ca[j]*8, Bs + (j*1024 + tid)*8);
  };
  stage(0, 0);
  __syncthreads();
  int cur = 0;
  for (int t = 0; t < nkt; ++t){
    if (t + 1 < nkt) stage(t + 1, cur ^ 1);   // issue first: full-tile latency lead
    const ushort* Ab = lds + cur*HALF;
    const ushort* Bb = Ab + 16384;
    f16x8 a0[4], a1[4], b0[NI], b1[NI];
    #pragma unroll
    for (int mi=0;mi<4;++mi){
      int r = wm + mi*16 + lr;
      a0[mi] = *(const f16x8*)&Ab[r*64 + ((kg     ^ (r&7))*8)];
      a1[mi] = *(const f16x8*)&Ab[r*64 + (((4+kg) ^ (r&7))*8)];
    }
    #pragma unroll
    for (int ni=0;ni<NI;++ni){
      int r = wn + ni*16 + lr;
      b0[ni] = *(const f16x8*)&Bb[r*64 + ((kg     ^ (r&7))*8)];
      b1[ni] = *(const f16x8*)&Bb[r*64 + (((4+kg) ^ (r&7))*8)];
    }
    __builtin_amdgcn_s_setprio(1);
    #pragma unroll
    for (int mi=0;mi<4;++mi)
      #pragma unroll
      for (int ni=0;ni<NI;++ni)
        acc[mi][ni] = __builtin_amdgcn_mfma_f32_16x16x32_f16(a0[mi], b0[ni], acc[mi][ni], 0,0,0);
    #pragma unroll
    for (int mi=0;mi<4;++mi)
      #pragma unroll
      for (int ni=0;ni<NI;++ni)
        acc[mi][ni] = __builtin_amdgcn_mfma_f32_16x16x32_f16(a1[mi], b1[ni], acc[mi][ni], 0,0,0);
    __builtin_amdgcn_s_setprio(0);
    __syncthreads();                          // drains vm+lgkm: buf^1 staged, buf free
    cur ^= 1;
  }
  // ---- epilogue: per-wave 64xWN transpose via LDS -> coalesced stores ----
  float* Lw = ((float*)lds) + w * 16 * WN;    // 16 waves x 16xWN f32 slices
  #pragma unroll
  for (int mi = 0; mi < 4; ++mi){
    #pragma unroll
    for (int ni = 0; ni < NI; ++ni)
      #pragma unroll
      for (int r = 0; r < 4; ++r)
        Lw[(kg*4+r)*WN + ni*16 + lr] = acc[mi][ni][r];
    __syncthreads();
    #pragma unroll
    for (int tt = 0; tt < WN/16; ++tt){       // 16*WN/4 float4s / 64 lanes
      int fi = tt*64 + lane;
      int row16 = fi / (WN/4), c4 = fi % (WN/4);
      float4 v4 = *(float4*)&Lw[row16*WN + c4*4];
      int row = m0 + wm + mi*16 + row16;
      int col = n0 + wn + c4*4;
      if (EPI==0){
        float4 b4 = *(const float4*)&bias[col];
        ushort4 o; o.x=f2h(v4.x+b4.x); o.y=f2h(v4.y+b4.y); o.z=f2h(v4.z+b4.z); o.w=f2h(v4.w+b4.w);
        *(ushort4*)&Ch[(long)row*N + col] = o;
      } else if (EPI==2){
        float4 e4 = *(const float4*)((const float*)extra + (long)row*N + col);
        ushort4 o; o.x=f2h(v4.x*alpha*e4.x); o.y=f2h(v4.y*alpha*e4.y);
        o.z=f2h(v4.z*alpha*e4.z); o.w=f2h(v4.w*alpha*e4.w);
        *(ushort4*)&Ch[(long)row*N + col] = o;
      } else if (EPI==3){
        float4 o; o.x=v4.x*alpha; o.y=v4.y*alpha; o.z=v4.z*alpha; o.w=v4.w*alpha;
        *(float4*)&Cf[(long)row*N + col] = o;
      } else if (EPI==4){
        float4 b4 = *(const float4*)&bias[col];
        ushort4 o; o.x=f2h(tanhf(v4.x+b4.x)); o.y=f2h(tanhf(v4.y+b4.y));
        o.z=f2h(tanhf(v4.z+b4.z)); o.w=f2h(tanhf(v4.w+b4.w));
        *(ushort4*)&Ch[(long)row*N + col] = o;
      } else if (EPI==5){
        float4 b4 = *(const float4*)&bias[col];
        ushort4 e4 = *(const ushort4*)((const ushort*)extra + (long)row*N + col);
        float4 o; o.x=v4.x+b4.x+h2f(e4.x); o.y=v4.y+b4.y+h2f(e4.y);
        o.z=v4.z+b4.z+h2f(e4.z); o.w=v4.w+b4.w+h2f(e4.w);
        *(float4*)&Cf[(long)row*N + col] = o;
      }
    }
    __syncthreads();
  }
}

// ---------- legacy 128x128 GEMM (for K, V^T, decoder) ----------
// EPI: 0 f16 out +bias | 1 f16 out transposed +bias | 6 f32 out +bias
template<int EPI, bool A32>
__global__ __launch_bounds__(256) void k_gemm(const void* __restrict__ Av, const ushort* __restrict__ Bt,
    int M, int N, int K, const float* __restrict__ bias,
    float alpha, float* __restrict__ Cf, ushort* __restrict__ Ch, int gxm1, int lg2gx)
{
  __shared__ ushort As[128*64];
  __shared__ ushort Bs[128*64];
  const int tid = threadIdx.x, lane = tid & 63, w = tid>>6;
  const int wm = (w>>1)*64, wn = (w&1)*64;
  int id = blockIdx.x;
  int nid = (id & 7)*((int)gridDim.x >> 3) + (id >> 3);
  const int m0 = (nid >> lg2gx)*128, n0 = (nid & gxm1)*128;
  const int lr = lane & 15, kg = lane >> 4;
  f32x4 acc[4][4] = {};
  const int nkt = K >> 6;
  const ushort* Ah = (const ushort*)Av + (A32 ? 0 : (long)m0*K);
  const float*  Af = (const float*)Av  + (A32 ? (long)m0*K : 0);
  const ushort* Bp = Bt + (long)n0*K;
  int rowj[4], colj[4];
  #pragma unroll
  for (int j=0;j<4;++j){
    int c = w*256 + j*64 + lane;
    rowj[j] = c>>3; colj[j] = (c&7) ^ (rowj[j]&7);
  }
  float4 pa[4][2];
  if (A32){
    #pragma unroll
    for (int j=0;j<4;++j){
      const float* s = Af + (long)rowj[j]*K + colj[j]*8;
      pa[j][0] = *(const float4*)s; pa[j][1] = *(const float4*)(s+4);
    }
  }
  for (int kt=0; kt<nkt; ++kt){
    __syncthreads();
    long ko = (long)kt*64;
    if (A32){
      #pragma unroll
      for (int j=0;j<4;++j){
        uint4 o; o.x=pk2(pa[j][0].x,pa[j][0].y); o.y=pk2(pa[j][0].z,pa[j][0].w);
        o.z=pk2(pa[j][1].x,pa[j][1].y); o.w=pk2(pa[j][1].z,pa[j][1].w);
        *(uint4*)&As[(w*256 + j*64 + lane)*8] = o;
      }
    } else {
      #pragma unroll
      for (int j=0;j<4;++j)
        gload16(Ah + (long)rowj[j]*K + ko + colj[j]*8, As + (w*4+j)*512);
    }
    #pragma unroll
    for (int j=0;j<4;++j)
      gload16(Bp + (long)rowj[j]*K + ko + colj[j]*8, Bs + (w*4+j)*512);
    __syncthreads();
    if (A32 && kt+1 < nkt){
      long ko2 = ko + 64;
      #pragma unroll
      for (int j=0;j<4;++j){
        const float* s = Af + (long)rowj[j]*K + ko2 + colj[j]*8;
        pa[j][0] = *(const float4*)s; pa[j][1] = *(const float4*)(s+4);
      }
    }
    #pragma unroll
    for (int ks=0; ks<2; ++ks){
      f16x8 af[4], bfr[4];
      #pragma unroll
      for (int mi=0;mi<4;++mi){
        int r = wm + mi*16 + lr, c = ks*4 + kg;
        af[mi] = *(const f16x8*)&As[r*64 + ((c ^ (r&7))*8)];
      }
      #pragma unroll
      for (int ni=0;ni<4;++ni){
        int r = wn + ni*16 + lr, c = ks*4 + kg;
        bfr[ni] = *(const f16x8*)&Bs[r*64 + ((c ^ (r&7))*8)];
      }
      #pragma unroll
      for (int mi=0;mi<4;++mi)
        #pragma unroll
        for (int ni=0;ni<4;++ni)
          acc[mi][ni] = __builtin_amdgcn_mfma_f32_16x16x32_f16(af[mi], bfr[ni], acc[mi][ni], 0,0,0);
    }
  }
  __syncthreads();
  float* Lw = ((float*)As) + w*1024;
  #pragma unroll
  for (int mi=0;mi<4;++mi){
    #pragma unroll
    for (int ni=0;ni<4;++ni)
      #pragma unroll
      for (int r=0;r<4;++r)
        Lw[(kg*4+r)*64 + ni*16 + lr] = acc[mi][ni][r];
    __syncthreads();
    #pragma unroll
    for (int t=0;t<4;++t){
      int fi = t*64 + lane;
      int row16 = fi >> 4, c4 = fi & 15;
      float4 v4 = *(float4*)&Lw[row16*64 + c4*4];
      int row = m0 + wm + mi*16 + row16;
      int col = n0 + wn + c4*4;
      if (EPI==0){
        float4 b4 = *(const float4*)&bias[col];
        ushort4 o; o.x=f2h(v4.x+b4.x); o.y=f2h(v4.y+b4.y); o.z=f2h(v4.z+b4.z); o.w=f2h(v4.w+b4.w);
        *(ushort4*)&Ch[(long)row*N + col] = o;
      } else if (EPI==1){
        float4 b4 = *(const float4*)&bias[col];
        Ch[(long)(col+0)*M + row] = f2h(v4.x+b4.x);
        Ch[(long)(col+1)*M + row] = f2h(v4.y+b4.y);
        Ch[(long)(col+2)*M + row] = f2h(v4.z+b4.z);
        Ch[(long)(col+3)*M + row] = f2h(v4.w+b4.w);
      } else {
        float4 b4 = *(const float4*)&bias[col];
        float4 o; o.x=v4.x+b4.x; o.y=v4.y+b4.y; o.z=v4.z+b4.z; o.w=v4.w+b4.w;
        *(float4*)&Cf[(long)row*N + col] = o;
      }
    }
    __syncthreads();
  }
}

// ---------- row softmax over 4096 f16 cols, writes prob*512 as f16 ----------
__global__ __launch_bounds__(256) void k_softmax(const ushort* __restrict__ S, ushort* __restrict__ P){
  const long base = (long)blockIdx.x * 4096;
  const int t = threadIdx.x;
  uint u[8];
  *(uint4*)&u[0] = *(const uint4*)(S + base + t*16);
  *(uint4*)&u[4] = *(const uint4*)(S + base + t*16 + 8);
  float v[16];
  #pragma unroll
  for (int i=0;i<8;++i){ v[2*i]=h2f((ushort)(u[i]&0xffff)); v[2*i+1]=h2f((ushort)(u[i]>>16)); }
  float mx = -3.4e38f;
  #pragma unroll
  for (int i=0;i<16;++i) mx = fmaxf(mx, v[i]);
  #pragma unroll
  for (int off=1; off<64; off<<=1) mx = fmaxf(mx, __shfl_xor(mx, off));
  __shared__ float red[8];
  int wv = t>>6;
  if ((t&63)==0) red[wv]=mx;
  __syncthreads();
  mx = fmaxf(fmaxf(red[0],red[1]), fmaxf(red[2],red[3]));
  float e[16]; float sum=0.f;
  #pragma unroll
  for (int i=0;i<16;++i){ e[i]=__expf(v[i]-mx); sum+=e[i]; }
  #pragma unroll
  for (int off=1; off<64; off<<=1) sum += __shfl_xor(sum, off);
  if ((t&63)==0) red[4+wv]=sum;
  __syncthreads();
  sum = red[4]+red[5]+red[6]+red[7];
  float s = 512.f/sum;
  uint o[8];
  #pragma unroll
  for (int i=0;i<8;++i) o[i]=pk2(e[2*i]*s, e[2*i+1]*s);
  *(uint4*)(P + base + t*16)     = *(uint4*)&o[0];
  *(uint4*)(P + base + t*16 + 8) = *(uint4*)&o[4];
}

// ---------- batchnorm: partial sums / finalize / apply ----------
__global__ __launch_bounds__(256) void k_bn_partial(const float* __restrict__ X, float* __restrict__ ps, float* __restrict__ pq, int F, int rowsPer){
  int col = blockIdx.x*256 + threadIdx.x;
  long r0 = (long)blockIdx.y * rowsPer;
  float s=0.f,q=0.f;
  for (int r=0;r<rowsPer;++r){ float x = X[(r0+r)*F + col]; s+=x; q+=x*x; }
  ps[(long)blockIdx.y*F + col]=s; pq[(long)blockIdx.y*F + col]=q;
}
__global__ __launch_bounds__(256) void k_bn_final(const float* __restrict__ ps, const float* __restrict__ pq,
    const float* __restrict__ gamma, const float* __restrict__ beta,
    float* __restrict__ scale, float* __restrict__ shift, int F, float invN, int nch){
  int c = blockIdx.x*256 + threadIdx.x;
  if (c>=F) return;
  float s=0.f,q=0.f;
  for (int i=0;i<nch;++i){ s+=ps[i*F+c]; q+=pq[i*F+c]; }
  float mu = s*invN, var = q*invN - mu*mu;
  float sc = gamma[c]*rsqrtf(var+1e-5f);
  scale[c]=sc; shift[c]=beta[c]-mu*sc;
}
__global__ __launch_bounds__(256) void k_bn_apply(const float* __restrict__ X, const float* __restrict__ scale, const float* __restrict__ shift,
    ushort* __restrict__ Xh, int F, long n){
  long i = ((long)blockIdx.x*256 + threadIdx.x)*4;
  if (i>=n) return;
  int c = (int)(i & (long)(F-1));
  float4 x = *(const float4*)(X+i);
  ushort4 o; o.x=f2h(x.x*scale[c]+shift[c]); o.y=f2h(x.y*scale[c+1]+shift[c+1]);
  o.z=f2h(x.z*scale[c+2]+shift[c+2]); o.w=f2h(x.w*scale[c+3]+shift[c+3]);
  *(ushort4*)(Xh+i)=o;
}
__global__ __launch_bounds__(256) void k_bn_tanh(const float* __restrict__ X, const float* __restrict__ scale, const float* __restrict__ shift,
    float* __restrict__ O, int F, long n){
  long i = ((long)blockIdx.x*256 + threadIdx.x)*4;
  if (i>=n) return;
  int c = (int)(i & (long)(F-1));
  float4 x = *(const float4*)(X+i);
  float4 y; y.x=tanhf(x.x*scale[c]+shift[c]); y.y=tanhf(x.y*scale[c+1]+shift[c+1]);
  y.z=tanhf(x.z*scale[c+2]+shift[c+2]); y.w=tanhf(x.w*scale[c+3]+shift[c+3]);
  *(float4*)(O+i)=y;
}

extern "C" void kernel_launch(void* const* d_in, const int* in_sizes, int n_in,
                              void* d_out, int out_size, void* d_ws, size_t ws_size,
                              hipStream_t stream){
  const float* src = (const float*)d_in[0];
  const float* a1  = (const float*)d_in[1];
  const float* a2  = (const float*)d_in[2];
  const float* lg  = (const float*)d_in[3];
  const float* Wq  = (const float*)d_in[4];
  const float* bq  = (const float*)d_in[5];
  const float* Wv  = (const float*)d_in[6];
  const float* bv  = (const float*)d_in[7];
  const float* W1  = (const float*)d_in[8];
  const float* b1  = (const float*)d_in[9];
  const float* W2  = (const float*)d_in[10];
  const float* b2  = (const float*)d_in[11];
  const float* g1  = (const float*)d_in[12];
  const float* be1 = (const float*)d_in[13];
  const float* g2  = (const float*)d_in[14];
  const float* be2 = (const float*)d_in[15];
  const float* Wd  = (const float*)d_in[16];
  const float* bd  = (const float*)d_in[17];
  const float* gd  = (const float*)d_in[18];
  const float* bed = (const float*)d_in[19];
  char* ws = (char*)d_ws;
  // region R0 (lifetime-aliased): src_h f16 [0,64M) -> scores f16 [0,64M) -> x_att f32 [0,32M)
  ushort* src_h = (ushort*)(ws + 0);
  ushort* scores= (ushort*)(ws + 0);
  float*  x_att = (float*) (ws + 0);
  ushort* xnb   = (ushort*)(ws + 67108864);
  ushort* hbuf  = (ushort*)(ws + 83886080);
  // region R1: prob f16 [128,192M) -> x2 f32 [128,160), x2nb [160,176), y [176,192)
  ushort* prob  = (ushort*)(ws + 134217728);
  float*  x2    = (float*) (ws + 134217728);
  ushort* x2nb  = (ushort*)(ws + 167772160);
  float*  y     = (float*) (ws + 184549376);
  // persistent (>=192MiB)
  ushort* Qh    = (ushort*)(ws + 201326592);
  ushort* Kh    = (ushort*)(ws + 218103808);
  ushort* VTh   = (ushort*)(ws + 226492416);
  ushort* WqT   = (ushort*)(ws + 234881024);
  ushort* WvT   = (ushort*)(ws + 243269632);
  ushort* W1T   = (ushort*)(ws + 244318208);
  ushort* W2T   = (ushort*)(ws + 248512512);
  ushort* WdT   = (ushort*)(ws + 252706816);
  float*  ps    = (float*) (ws + 253755392);
  float*  pq    = (float*) (ws + 253886464);
  float*  sc1   = (float*) (ws + 254017536);
  float*  sh1   = (float*) (ws + 254021632);
  float*  sc2   = (float*) (ws + 254025728);
  float*  sh2   = (float*) (ws + 254029824);
  float*  scd   = (float*) (ws + 254033920);
  float*  shd   = (float*) (ws + 254035968);

  (void)hipFuncSetAttribute((const void*)k_gemmT<0,0>, hipFuncAttributeMaxDynamicSharedMemorySize, 98304);
  (void)hipFuncSetAttribute((const void*)k_gemmT<3,0>, hipFuncAttributeMaxDynamicSharedMemorySize, 98304);
  (void)hipFuncSetAttribute((const void*)k_gemmT<5,0>, hipFuncAttributeMaxDynamicSharedMemorySize, 98304);
  (void)hipFuncSetAttribute((const void*)k_gemmT<2,1>, hipFuncAttributeMaxDynamicSharedMemorySize, 131072);
  (void)hipFuncSetAttribute((const void*)k_gemmT<4,1>, hipFuncAttributeMaxDynamicSharedMemorySize, 131072);

  dim3 b256(256), b1024(1024);
  k_conv<<<dim3(16384), b256, 0, stream>>>(src, src_h, (long)NSRC*QDIM);
  k_prep<<<dim3(9216), b256, 0, stream>>>(Wq, Wv, W1, W2, Wd, WqT, WvT, W1T, W2T, WdT);
  // Q (SMALL 16-wave), K and V^T (legacy, fused f32 A)
  k_gemmT<0,0><<<dim3(256), b1024, 98304, stream>>>(src_h, WqT, NSRC, DM, QDIM, bq, nullptr, 1.f, nullptr, Qh, 7, 3);
  k_gemm<0,true><<<dim3(256), b256, 0, stream>>>(a1, WqT, MANC, DM, QDIM, bq, 1.f, nullptr, Kh, 7, 3);
  k_gemm<1,true><<<dim3(256), b256, 0, stream>>>(a2, WvT, MANC, DM, VDIM, bv, 1.f, nullptr, VTh, 7, 3);
  // scores(f16) = (Q K^T)/32 * label_graph ; softmax(f16) ; x = prob V
  k_gemmT<2,1><<<dim3(512), b1024, 131072, stream>>>(Qh, Kh, NSRC, MANC, DM, nullptr, lg, 0.03125f, nullptr, scores, 15, 4);
  k_softmax<<<dim3(NSRC), b256, 0, stream>>>(scores, prob);
  k_gemmT<3,0><<<dim3(256), b1024, 98304, stream>>>(prob, VTh, NSRC, DM, MANC, nullptr, nullptr, 1.f/512.f, x_att, nullptr, 7, 3);
  // BN1
  k_bn_partial<<<dim3(DM/256, 32), b256, 0, stream>>>(x_att, ps, pq, DM, NSRC/32);
  k_bn_final<<<dim3(DM/256), b256, 0, stream>>>(ps, pq, g1, be1, sc1, sh1, DM, 1.f/NSRC, 32);
  k_bn_apply<<<dim3(8192), b256, 0, stream>>>(x_att, sc1, sh1, xnb, DM, (long)NSRC*DM);
  // FFN
  k_gemmT<4,1><<<dim3(256), b1024, 131072, stream>>>(xnb, W1T, NSRC, FFD, DM, b1, nullptr, 1.f, nullptr, hbuf, 7, 3);
  k_gemmT<5,0><<<dim3(256), b1024, 98304, stream>>>(hbuf, W2T, NSRC, DM, FFD, b2, xnb, 1.f, x2, nullptr, 7, 3);
  // BN2
  k_bn_partial<<<dim3(DM/256, 32), b256, 0, stream>>>(x2, ps, pq, DM, NSRC/32);
  k_bn_final<<<dim3(DM/256), b256, 0, stream>>>(ps, pq, g2, be2, sc2, sh2, DM, 1.f/NSRC, 32);
  k_bn_apply<<<dim3(8192), b256, 0, stream>>>(x2, sc2, sh2, x2nb, DM, (long)NSRC*DM);
  // decoder + BN + tanh
  k_gemm<6,false><<<dim3(256), b256, 0, stream>>>(x2nb, WdT, NSRC, VDIM, DM, bd, 1.f, y, nullptr, 3, 2);
  k_bn_partial<<<dim3(VDIM/256, 32), b256, 0, stream>>>(y, ps, pq, VDIM, NSRC/32);
  k_bn_final<<<dim3(2), b256, 0, stream>>>(ps, pq, gd, bed, scd, shd, VDIM, 1.f/NSRC, 32);
  k_bn_tanh<<<dim3(4096), b256, 0, stream>>>(y, scd, shd, (float*)d_out, VDIM, (long)NSRC*VDIM);
}

// Round 9
// 764.021 us; speedup vs baseline: 1.1867x; 1.1867x over previous
//
#include <hip/hip_runtime.h>

typedef __attribute__((ext_vector_type(4))) float f32x4;
typedef __attribute__((ext_vector_type(8))) _Float16 f16x8;

#define NSRC 8192
#define MANC 4096
#define QDIM 4096
#define VDIM 512
#define DM   1024
#define FFD  2048

__device__ __forceinline__ ushort f2h(float f){ _Float16 h=(_Float16)f; return __builtin_bit_cast(ushort,h); }
__device__ __forceinline__ float h2f(ushort u){ _Float16 h=__builtin_bit_cast(_Float16,u); return (float)h; }
__device__ __forceinline__ uint pk2(float a,float b){ return (uint)f2h(a) | ((uint)f2h(b)<<16); }

__device__ __forceinline__ void gload16(const ushort* g, ushort* l){
  __builtin_amdgcn_global_load_lds(
    (const __attribute__((address_space(1))) unsigned int*)g,
    (__attribute__((address_space(3))) unsigned int*)l, 16, 0, 0);
}

// ---------- f32 -> f16 convert (src only) ----------
__global__ __launch_bounds__(256) void k_conv(const float* __restrict__ in, ushort* __restrict__ out, long n){
  long i = ((long)blockIdx.x*256 + threadIdx.x)*8;
  if (i >= n) return;
  float4 a = *(const float4*)(in+i);
  float4 b = *(const float4*)(in+i+4);
  uint4 o; o.x=pk2(a.x,a.y); o.y=pk2(a.z,a.w); o.z=pk2(b.x,b.y); o.w=pk2(b.z,b.w);
  *(uint4*)(out+i) = o;
}

// ---------- merged weight transposes: W[K][N] f32 -> WT[N][K] f16 ----------
__device__ __forceinline__ void tr32(const float* __restrict__ W, ushort* __restrict__ WT,
                                     int K, int N, int bx, int by, int tid){
  __shared__ float tile[32][33];
  int n0 = bx*32, k0 = by*32;
  int tx = tid & 31, ty = tid >> 5;
  #pragma unroll
  for (int i=0;i<4;++i) tile[ty+i*8][tx] = W[(long)(k0+ty+i*8)*N + n0+tx];
  __syncthreads();
  #pragma unroll
  for (int i=0;i<4;++i){ int nn=ty+i*8; WT[(long)(n0+nn)*K + k0+tx] = f2h(tile[tx][nn]); }
}
__global__ __launch_bounds__(256) void k_prep(const float* __restrict__ Wq, const float* __restrict__ Wv,
    const float* __restrict__ W1, const float* __restrict__ W2, const float* __restrict__ Wd,
    ushort* __restrict__ WqT, ushort* __restrict__ WvT, ushort* __restrict__ W1T,
    ushort* __restrict__ W2T, ushort* __restrict__ WdT){
  int b = blockIdx.x, t = threadIdx.x;
  if (b < 4096)                 tr32(Wq, WqT, QDIM, DM,  b % 32,        b / 32,        t);
  else if (b < 4608)            tr32(Wv, WvT, VDIM, DM,  (b-4096)%32,   (b-4096)/32,   t);
  else if (b < 6656)            tr32(W1, W1T, DM,  FFD,  (b-4608)%64,   (b-4608)/64,   t);
  else if (b < 8704)            tr32(W2, W2T, FFD, DM,   (b-6656)%32,   (b-6656)/32,   t);
  else                          tr32(Wd, WdT, DM,  VDIM, (b-8704)%16,   (b-8704)/16,   t);
}

// ============ 16-wave TLP GEMM: 1024 thr, 256xBN tile, double-buffered ============
// __launch_bounds__(1024,4): 4 waves/EU min = exactly 1 block/CU -> VGPR cap 128
// (round 8's plain (1024) let the compiler target 64 VGPR for an impossible
// 2-block residency and spilled the accumulators: WRITE_SIZE 406MB of scratch).
// Frag reads split per ks-half to keep peak live regs ~120: read ks0 -> MFMA ks0
// -> read ks1 -> MFMA ks1. 4 waves/SIMD cover the serialized ds_read latency.
// EPI: 0 f16+bias | 2 f16 *alpha*extra(f32) | 3 f32 *alpha | 4 f16 tanh(+bias) | 5 f32 +bias+extra(f16)
template<int EPI, int BIG>
__global__ __launch_bounds__(1024, 4) void k_gemmT(const ushort* __restrict__ A, const ushort* __restrict__ Bt,
    int M, int N, int K, const float* __restrict__ bias, const void* __restrict__ extra,
    float alpha, float* __restrict__ Cf, ushort* __restrict__ Ch, int gxm1, int lg2gx)
{
  extern __shared__ ushort lds[];
  constexpr int BN   = BIG ? 256 : 128;
  constexpr int NI   = BIG ? 4 : 2;          // acc cols per wave
  constexpr int WN   = NI * 16;              // per-wave N width
  constexpr int BSH  = BIG ? 16384 : 8192;   // shorts per B buffer
  constexpr int HALF = 16384 + BSH;          // shorts per (A,B) buffer
  constexpr int BJ   = BIG ? 2 : 1;          // B stage loads per thread
  const int tid = threadIdx.x, lane = tid & 63, w = tid >> 6;
  const int wm = (w >> 2) * 64, wn = (w & 3) * WN;
  int id = blockIdx.x;
  int nid = (id & 7) * ((int)gridDim.x >> 3) + (id >> 3);
  const int m0 = (nid >> lg2gx) * 256, n0 = (nid & gxm1) * BN;
  const int lr = lane & 15, kg = lane >> 4;
  f32x4 acc[4][NI] = {};
  const int nkt = K >> 6;
  const ushort* Ap = A + (long)m0 * K;
  const ushort* Bp = Bt + (long)n0 * K;
  // staging map: 16B chunk c -> row c>>3, col-chunk (c&7)^(row&7) (XOR both sides)
  int ra[2], ca[2];
  #pragma unroll
  for (int j = 0; j < 2; ++j){ int c = j*1024 + tid; ra[j] = c >> 3; ca[j] = (c & 7) ^ (ra[j] & 7); }
  auto stage = [&](int t, int buf){
    long ko = (long)t * 64;
    ushort* As = lds + buf*HALF;
    ushort* Bs = As + 16384;
    #pragma unroll
    for (int j = 0; j < 2; ++j)  gload16(Ap + (long)ra[j]*K + ko + ca[j]*8, As + (j*1024 + tid)*8);
    #pragma unroll
    for (int j = 0; j < BJ; ++j) gload16(Bp + (long)ra[j]*K + ko + ca[j]*8, Bs + (j*1024 + tid)*8);
  };
  stage(0, 0);
  __syncthreads();
  int cur = 0;
  for (int t = 0; t < nkt; ++t){
    if (t + 1 < nkt) stage(t + 1, cur ^ 1);   // issue first: full-tile latency lead
    const ushort* Ab = lds + cur*HALF;
    const ushort* Bb = Ab + 16384;
    f16x8 af[4], bf[NI];
    // ---- ks0 ----
    #pragma unroll
    for (int mi=0;mi<4;++mi){ int r = wm + mi*16 + lr; af[mi] = *(const f16x8*)&Ab[r*64 + ((kg ^ (r&7))*8)]; }
    #pragma unroll
    for (int ni=0;ni<NI;++ni){ int r = wn + ni*16 + lr; bf[ni] = *(const f16x8*)&Bb[r*64 + ((kg ^ (r&7))*8)]; }
    __builtin_amdgcn_s_setprio(1);
    #pragma unroll
    for (int mi=0;mi<4;++mi)
      #pragma unroll
      for (int ni=0;ni<NI;++ni)
        acc[mi][ni] = __builtin_amdgcn_mfma_f32_16x16x32_f16(af[mi], bf[ni], acc[mi][ni], 0,0,0);
    __builtin_amdgcn_s_setprio(0);
    // ---- ks1 ----
    #pragma unroll
    for (int mi=0;mi<4;++mi){ int r = wm + mi*16 + lr; af[mi] = *(const f16x8*)&Ab[r*64 + (((4+kg) ^ (r&7))*8)]; }
    #pragma unroll
    for (int ni=0;ni<NI;++ni){ int r = wn + ni*16 + lr; bf[ni] = *(const f16x8*)&Bb[r*64 + (((4+kg) ^ (r&7))*8)]; }
    __builtin_amdgcn_s_setprio(1);
    #pragma unroll
    for (int mi=0;mi<4;++mi)
      #pragma unroll
      for (int ni=0;ni<NI;++ni)
        acc[mi][ni] = __builtin_amdgcn_mfma_f32_16x16x32_f16(af[mi], bf[ni], acc[mi][ni], 0,0,0);
    __builtin_amdgcn_s_setprio(0);
    __syncthreads();                          // drains vm+lgkm: buf^1 staged, buf free
    cur ^= 1;
  }
  // ---- epilogue: per-wave 64xWN transpose via LDS -> coalesced stores ----
  float* Lw = ((float*)lds) + w * 16 * WN;    // 16 waves x 16xWN f32 slices
  #pragma unroll
  for (int mi = 0; mi < 4; ++mi){
    #pragma unroll
    for (int ni = 0; ni < NI; ++ni)
      #pragma unroll
      for (int r = 0; r < 4; ++r)
        Lw[(kg*4+r)*WN + ni*16 + lr] = acc[mi][ni][r];
    __syncthreads();
    #pragma unroll
    for (int tt = 0; tt < WN/16; ++tt){
      int fi = tt*64 + lane;
      int row16 = fi / (WN/4), c4 = fi % (WN/4);
      float4 v4 = *(float4*)&Lw[row16*WN + c4*4];
      int row = m0 + wm + mi*16 + row16;
      int col = n0 + wn + c4*4;
      if (EPI==0){
        float4 b4 = *(const float4*)&bias[col];
        ushort4 o; o.x=f2h(v4.x+b4.x); o.y=f2h(v4.y+b4.y); o.z=f2h(v4.z+b4.z); o.w=f2h(v4.w+b4.w);
        *(ushort4*)&Ch[(long)row*N + col] = o;
      } else if (EPI==2){
        float4 e4 = *(const float4*)((const float*)extra + (long)row*N + col);
        ushort4 o; o.x=f2h(v4.x*alpha*e4.x); o.y=f2h(v4.y*alpha*e4.y);
        o.z=f2h(v4.z*alpha*e4.z); o.w=f2h(v4.w*alpha*e4.w);
        *(ushort4*)&Ch[(long)row*N + col] = o;
      } else if (EPI==3){
        float4 o; o.x=v4.x*alpha; o.y=v4.y*alpha; o.z=v4.z*alpha; o.w=v4.w*alpha;
        *(float4*)&Cf[(long)row*N + col] = o;
      } else if (EPI==4){
        float4 b4 = *(const float4*)&bias[col];
        ushort4 o; o.x=f2h(tanhf(v4.x+b4.x)); o.y=f2h(tanhf(v4.y+b4.y));
        o.z=f2h(tanhf(v4.z+b4.z)); o.w=f2h(tanhf(v4.w+b4.w));
        *(ushort4*)&Ch[(long)row*N + col] = o;
      } else if (EPI==5){
        float4 b4 = *(const float4*)&bias[col];
        ushort4 e4 = *(const ushort4*)((const ushort*)extra + (long)row*N + col);
        float4 o; o.x=v4.x+b4.x+h2f(e4.x); o.y=v4.y+b4.y+h2f(e4.y);
        o.z=v4.z+b4.z+h2f(e4.z); o.w=v4.w+b4.w+h2f(e4.w);
        *(float4*)&Cf[(long)row*N + col] = o;
      }
    }
    __syncthreads();
  }
}

// ---------- legacy 128x128 GEMM (for K, V^T, decoder) ----------
// EPI: 0 f16 out +bias | 1 f16 out transposed +bias | 6 f32 out +bias
template<int EPI, bool A32>
__global__ __launch_bounds__(256) void k_gemm(const void* __restrict__ Av, const ushort* __restrict__ Bt,
    int M, int N, int K, const float* __restrict__ bias,
    float alpha, float* __restrict__ Cf, ushort* __restrict__ Ch, int gxm1, int lg2gx)
{
  __shared__ ushort As[128*64];
  __shared__ ushort Bs[128*64];
  const int tid = threadIdx.x, lane = tid & 63, w = tid>>6;
  const int wm = (w>>1)*64, wn = (w&1)*64;
  int id = blockIdx.x;
  int nid = (id & 7)*((int)gridDim.x >> 3) + (id >> 3);
  const int m0 = (nid >> lg2gx)*128, n0 = (nid & gxm1)*128;
  const int lr = lane & 15, kg = lane >> 4;
  f32x4 acc[4][4] = {};
  const int nkt = K >> 6;
  const ushort* Ah = (const ushort*)Av + (A32 ? 0 : (long)m0*K);
  const float*  Af = (const float*)Av  + (A32 ? (long)m0*K : 0);
  const ushort* Bp = Bt + (long)n0*K;
  int rowj[4], colj[4];
  #pragma unroll
  for (int j=0;j<4;++j){
    int c = w*256 + j*64 + lane;
    rowj[j] = c>>3; colj[j] = (c&7) ^ (rowj[j]&7);
  }
  float4 pa[4][2];
  if (A32){
    #pragma unroll
    for (int j=0;j<4;++j){
      const float* s = Af + (long)rowj[j]*K + colj[j]*8;
      pa[j][0] = *(const float4*)s; pa[j][1] = *(const float4*)(s+4);
    }
  }
  for (int kt=0; kt<nkt; ++kt){
    __syncthreads();
    long ko = (long)kt*64;
    if (A32){
      #pragma unroll
      for (int j=0;j<4;++j){
        uint4 o; o.x=pk2(pa[j][0].x,pa[j][0].y); o.y=pk2(pa[j][0].z,pa[j][0].w);
        o.z=pk2(pa[j][1].x,pa[j][1].y); o.w=pk2(pa[j][1].z,pa[j][1].w);
        *(uint4*)&As[(w*256 + j*64 + lane)*8] = o;
      }
    } else {
      #pragma unroll
      for (int j=0;j<4;++j)
        gload16(Ah + (long)rowj[j]*K + ko + colj[j]*8, As + (w*4+j)*512);
    }
    #pragma unroll
    for (int j=0;j<4;++j)
      gload16(Bp + (long)rowj[j]*K + ko + colj[j]*8, Bs + (w*4+j)*512);
    __syncthreads();
    if (A32 && kt+1 < nkt){
      long ko2 = ko + 64;
      #pragma unroll
      for (int j=0;j<4;++j){
        const float* s = Af + (long)rowj[j]*K + ko2 + colj[j]*8;
        pa[j][0] = *(const float4*)s; pa[j][1] = *(const float4*)(s+4);
      }
    }
    #pragma unroll
    for (int ks=0; ks<2; ++ks){
      f16x8 af[4], bfr[4];
      #pragma unroll
      for (int mi=0;mi<4;++mi){
        int r = wm + mi*16 + lr, c = ks*4 + kg;
        af[mi] = *(const f16x8*)&As[r*64 + ((c ^ (r&7))*8)];
      }
      #pragma unroll
      for (int ni=0;ni<4;++ni){
        int r = wn + ni*16 + lr, c = ks*4 + kg;
        bfr[ni] = *(const f16x8*)&Bs[r*64 + ((c ^ (r&7))*8)];
      }
      #pragma unroll
      for (int mi=0;mi<4;++mi)
        #pragma unroll
        for (int ni=0;ni<4;++ni)
          acc[mi][ni] = __builtin_amdgcn_mfma_f32_16x16x32_f16(af[mi], bfr[ni], acc[mi][ni], 0,0,0);
    }
  }
  __syncthreads();
  float* Lw = ((float*)As) + w*1024;
  #pragma unroll
  for (int mi=0;mi<4;++mi){
    #pragma unroll
    for (int ni=0;ni<4;++ni)
      #pragma unroll
      for (int r=0;r<4;++r)
        Lw[(kg*4+r)*64 + ni*16 + lr] = acc[mi][ni][r];
    __syncthreads();
    #pragma unroll
    for (int t=0;t<4;++t){
      int fi = t*64 + lane;
      int row16 = fi >> 4, c4 = fi & 15;
      float4 v4 = *(float4*)&Lw[row16*64 + c4*4];
      int row = m0 + wm + mi*16 + row16;
      int col = n0 + wn + c4*4;
      if (EPI==0){
        float4 b4 = *(const float4*)&bias[col];
        ushort4 o; o.x=f2h(v4.x+b4.x); o.y=f2h(v4.y+b4.y); o.z=f2h(v4.z+b4.z); o.w=f2h(v4.w+b4.w);
        *(ushort4*)&Ch[(long)row*N + col] = o;
      } else if (EPI==1){
        float4 b4 = *(const float4*)&bias[col];
        Ch[(long)(col+0)*M + row] = f2h(v4.x+b4.x);
        Ch[(long)(col+1)*M + row] = f2h(v4.y+b4.y);
        Ch[(long)(col+2)*M + row] = f2h(v4.z+b4.z);
        Ch[(long)(col+3)*M + row] = f2h(v4.w+b4.w);
      } else {
        float4 b4 = *(const float4*)&bias[col];
        float4 o; o.x=v4.x+b4.x; o.y=v4.y+b4.y; o.z=v4.z+b4.z; o.w=v4.w+b4.w;
        *(float4*)&Cf[(long)row*N + col] = o;
      }
    }
    __syncthreads();
  }
}

// ---------- row softmax over 4096 f16 cols, writes prob*512 as f16 ----------
__global__ __launch_bounds__(256) void k_softmax(const ushort* __restrict__ S, ushort* __restrict__ P){
  const long base = (long)blockIdx.x * 4096;
  const int t = threadIdx.x;
  uint u[8];
  *(uint4*)&u[0] = *(const uint4*)(S + base + t*16);
  *(uint4*)&u[4] = *(const uint4*)(S + base + t*16 + 8);
  float v[16];
  #pragma unroll
  for (int i=0;i<8;++i){ v[2*i]=h2f((ushort)(u[i]&0xffff)); v[2*i+1]=h2f((ushort)(u[i]>>16)); }
  float mx = -3.4e38f;
  #pragma unroll
  for (int i=0;i<16;++i) mx = fmaxf(mx, v[i]);
  #pragma unroll
  for (int off=1; off<64; off<<=1) mx = fmaxf(mx, __shfl_xor(mx, off));
  __shared__ float red[8];
  int wv = t>>6;
  if ((t&63)==0) red[wv]=mx;
  __syncthreads();
  mx = fmaxf(fmaxf(red[0],red[1]), fmaxf(red[2],red[3]));
  float e[16]; float sum=0.f;
  #pragma unroll
  for (int i=0;i<16;++i){ e[i]=__expf(v[i]-mx); sum+=e[i]; }
  #pragma unroll
  for (int off=1; off<64; off<<=1) sum += __shfl_xor(sum, off);
  if ((t&63)==0) red[4+wv]=sum;
  __syncthreads();
  sum = red[4]+red[5]+red[6]+red[7];
  float s = 512.f/sum;
  uint o[8];
  #pragma unroll
  for (int i=0;i<8;++i) o[i]=pk2(e[2*i]*s, e[2*i+1]*s);
  *(uint4*)(P + base + t*16)     = *(uint4*)&o[0];
  *(uint4*)(P + base + t*16 + 8) = *(uint4*)&o[4];
}

// ---------- batchnorm: partial sums / finalize / apply ----------
__global__ __launch_bounds__(256) void k_bn_partial(const float* __restrict__ X, float* __restrict__ ps, float* __restrict__ pq, int F, int rowsPer){
  int col = blockIdx.x*256 + threadIdx.x;
  long r0 = (long)blockIdx.y * rowsPer;
  float s=0.f,q=0.f;
  for (int r=0;r<rowsPer;++r){ float x = X[(r0+r)*F + col]; s+=x; q+=x*x; }
  ps[(long)blockIdx.y*F + col]=s; pq[(long)blockIdx.y*F + col]=q;
}
__global__ __launch_bounds__(256) void k_bn_final(const float* __restrict__ ps, const float* __restrict__ pq,
    const float* __restrict__ gamma, const float* __restrict__ beta,
    float* __restrict__ scale, float* __restrict__ shift, int F, float invN, int nch){
  int c = blockIdx.x*256 + threadIdx.x;
  if (c>=F) return;
  float s=0.f,q=0.f;
  for (int i=0;i<nch;++i){ s+=ps[i*F+c]; q+=pq[i*F+c]; }
  float mu = s*invN, var = q*invN - mu*mu;
  float sc = gamma[c]*rsqrtf(var+1e-5f);
  scale[c]=sc; shift[c]=beta[c]-mu*sc;
}
__global__ __launch_bounds__(256) void k_bn_apply(const float* __restrict__ X, const float* __restrict__ scale, const float* __restrict__ shift,
    ushort* __restrict__ Xh, int F, long n){
  long i = ((long)blockIdx.x*256 + threadIdx.x)*4;
  if (i>=n) return;
  int c = (int)(i & (long)(F-1));
  float4 x = *(const float4*)(X+i);
  ushort4 o; o.x=f2h(x.x*scale[c]+shift[c]); o.y=f2h(x.y*scale[c+1]+shift[c+1]);
  o.z=f2h(x.z*scale[c+2]+shift[c+2]); o.w=f2h(x.w*scale[c+3]+shift[c+3]);
  *(ushort4*)(Xh+i)=o;
}
__global__ __launch_bounds__(256) void k_bn_tanh(const float* __restrict__ X, const float* __restrict__ scale, const float* __restrict__ shift,
    float* __restrict__ O, int F, long n){
  long i = ((long)blockIdx.x*256 + threadIdx.x)*4;
  if (i>=n) return;
  int c = (int)(i & (long)(F-1));
  float4 x = *(const float4*)(X+i);
  float4 y; y.x=tanhf(x.x*scale[c]+shift[c]); y.y=tanhf(x.y*scale[c+1]+shift[c+1]);
  y.z=tanhf(x.z*scale[c+2]+shift[c+2]); y.w=tanhf(x.w*scale[c+3]+shift[c+3]);
  *(float4*)(O+i)=y;
}

extern "C" void kernel_launch(void* const* d_in, const int* in_sizes, int n_in,
                              void* d_out, int out_size, void* d_ws, size_t ws_size,
                              hipStream_t stream){
  const float* src = (const float*)d_in[0];
  const float* a1  = (const float*)d_in[1];
  const float* a2  = (const float*)d_in[2];
  const float* lg  = (const float*)d_in[3];
  const float* Wq  = (const float*)d_in[4];
  const float* bq  = (const float*)d_in[5];
  const float* Wv  = (const float*)d_in[6];
  const float* bv  = (const float*)d_in[7];
  const float* W1  = (const float*)d_in[8];
  const float* b1  = (const float*)d_in[9];
  const float* W2  = (const float*)d_in[10];
  const float* b2  = (const float*)d_in[11];
  const float* g1  = (const float*)d_in[12];
  const float* be1 = (const float*)d_in[13];
  const float* g2  = (const float*)d_in[14];
  const float* be2 = (const float*)d_in[15];
  const float* Wd  = (const float*)d_in[16];
  const float* bd  = (const float*)d_in[17];
  const float* gd  = (const float*)d_in[18];
  const float* bed = (const float*)d_in[19];
  char* ws = (char*)d_ws;
  // region R0 (lifetime-aliased): src_h f16 [0,64M) -> scores f16 [0,64M) -> x_att f32 [0,32M)
  ushort* src_h = (ushort*)(ws + 0);
  ushort* scores= (ushort*)(ws + 0);
  float*  x_att = (float*) (ws + 0);
  ushort* xnb   = (ushort*)(ws + 67108864);
  ushort* hbuf  = (ushort*)(ws + 83886080);
  // region R1: prob f16 [128,192M) -> x2 f32 [128,160), x2nb [160,176), y [176,192)
  ushort* prob  = (ushort*)(ws + 134217728);
  float*  x2    = (float*) (ws + 134217728);
  ushort* x2nb  = (ushort*)(ws + 167772160);
  float*  y     = (float*) (ws + 184549376);
  // persistent (>=192MiB)
  ushort* Qh    = (ushort*)(ws + 201326592);
  ushort* Kh    = (ushort*)(ws + 218103808);
  ushort* VTh   = (ushort*)(ws + 226492416);
  ushort* WqT   = (ushort*)(ws + 234881024);
  ushort* WvT   = (ushort*)(ws + 243269632);
  ushort* W1T   = (ushort*)(ws + 244318208);
  ushort* W2T   = (ushort*)(ws + 248512512);
  ushort* WdT   = (ushort*)(ws + 252706816);
  float*  ps    = (float*) (ws + 253755392);
  float*  pq    = (float*) (ws + 253886464);
  float*  sc1   = (float*) (ws + 254017536);
  float*  sh1   = (float*) (ws + 254021632);
  float*  sc2   = (float*) (ws + 254025728);
  float*  sh2   = (float*) (ws + 254029824);
  float*  scd   = (float*) (ws + 254033920);
  float*  shd   = (float*) (ws + 254035968);

  (void)hipFuncSetAttribute((const void*)k_gemmT<0,0>, hipFuncAttributeMaxDynamicSharedMemorySize, 98304);
  (void)hipFuncSetAttribute((const void*)k_gemmT<3,0>, hipFuncAttributeMaxDynamicSharedMemorySize, 98304);
  (void)hipFuncSetAttribute((const void*)k_gemmT<5,0>, hipFuncAttributeMaxDynamicSharedMemorySize, 98304);
  (void)hipFuncSetAttribute((const void*)k_gemmT<2,1>, hipFuncAttributeMaxDynamicSharedMemorySize, 131072);
  (void)hipFuncSetAttribute((const void*)k_gemmT<4,1>, hipFuncAttributeMaxDynamicSharedMemorySize, 131072);

  dim3 b256(256), b1024(1024);
  k_conv<<<dim3(16384), b256, 0, stream>>>(src, src_h, (long)NSRC*QDIM);
  k_prep<<<dim3(9216), b256, 0, stream>>>(Wq, Wv, W1, W2, Wd, WqT, WvT, W1T, W2T, WdT);
  // Q (SMALL 16-wave), K and V^T (legacy, fused f32 A)
  k_gemmT<0,0><<<dim3(256), b1024, 98304, stream>>>(src_h, WqT, NSRC, DM, QDIM, bq, nullptr, 1.f, nullptr, Qh, 7, 3);
  k_gemm<0,true><<<dim3(256), b256, 0, stream>>>(a1, WqT, MANC, DM, QDIM, bq, 1.f, nullptr, Kh, 7, 3);
  k_gemm<1,true><<<dim3(256), b256, 0, stream>>>(a2, WvT, MANC, DM, VDIM, bv, 1.f, nullptr, VTh, 7, 3);
  // scores(f16) = (Q K^T)/32 * label_graph ; softmax(f16) ; x = prob V
  k_gemmT<2,1><<<dim3(512), b1024, 131072, stream>>>(Qh, Kh, NSRC, MANC, DM, nullptr, lg, 0.03125f, nullptr, scores, 15, 4);
  k_softmax<<<dim3(NSRC), b256, 0, stream>>>(scores, prob);
  k_gemmT<3,0><<<dim3(256), b1024, 98304, stream>>>(prob, VTh, NSRC, DM, MANC, nullptr, nullptr, 1.f/512.f, x_att, nullptr, 7, 3);
  // BN1
  k_bn_partial<<<dim3(DM/256, 32), b256, 0, stream>>>(x_att, ps, pq, DM, NSRC/32);
  k_bn_final<<<dim3(DM/256), b256, 0, stream>>>(ps, pq, g1, be1, sc1, sh1, DM, 1.f/NSRC, 32);
  k_bn_apply<<<dim3(8192), b256, 0, stream>>>(x_att, sc1, sh1, xnb, DM, (long)NSRC*DM);
  // FFN
  k_gemmT<4,1><<<dim3(256), b1024, 131072, stream>>>(xnb, W1T, NSRC, FFD, DM, b1, nullptr, 1.f, nullptr, hbuf, 7, 3);
  k_gemmT<5,0><<<dim3(256), b1024, 98304, stream>>>(hbuf, W2T, NSRC, DM, FFD, b2, xnb, 1.f, x2, nullptr, 7, 3);
  // BN2
  k_bn_partial<<<dim3(DM/256, 32), b256, 0, stream>>>(x2, ps, pq, DM, NSRC/32);
  k_bn_final<<<dim3(DM/256), b256, 0, stream>>>(ps, pq, g2, be2, sc2, sh2, DM, 1.f/NSRC, 32);
  k_bn_apply<<<dim3(8192), b256, 0, stream>>>(x2, sc2, sh2, x2nb, DM, (long)NSRC*DM);
  // decoder + BN + tanh
  k_gemm<6,false><<<dim3(256), b256, 0, stream>>>(x2nb, WdT, NSRC, VDIM, DM, bd, 1.f, y, nullptr, 3, 2);
  k_bn_partial<<<dim3(VDIM/256, 32), b256, 0, stream>>>(y, ps, pq, VDIM, NSRC/32);
  k_bn_final<<<dim3(2), b256, 0, stream>>>(ps, pq, gd, bed, scd, shd, VDIM, 1.f/NSRC, 32);
  k_bn_tanh<<<dim3(4096), b256, 0, stream>>>(y, scd, shd, (float*)d_out, VDIM, (long)NSRC*VDIM);
}